// Round 1
// baseline (4385.399 us; speedup 1.0000x reference)
//
#include <hip/hip_runtime.h>

// ---------------------------------------------------------------------------
// GCN 2-layer forward:
//   deg/dinv/norm -> h1 = x@W1 -> scatter-add(norm*h1[row] -> agg[col])
//   x2 = relu(agg + h1*dinv^2 + b1) -> h2 = x2@W2 -> scatter -> out + self + b2
// ---------------------------------------------------------------------------

__global__ __launch_bounds__(256) void deg_kernel(const int* __restrict__ col,
                                                  float* __restrict__ deg, int E) {
    int i = blockIdx.x * 256 + threadIdx.x;
    if (i < E) atomicAdd(&deg[col[i]], 1.0f);
}

__global__ __launch_bounds__(256) void dinv_kernel(float* __restrict__ deg, int N) {
    int i = blockIdx.x * 256 + threadIdx.x;
    if (i < N) deg[i] = rsqrtf(deg[i] + 1.0f);   // +1 for self-loop
}

__global__ __launch_bounds__(256) void norm_kernel(const int* __restrict__ row,
                                                   const int* __restrict__ col,
                                                   const float* __restrict__ dinv,
                                                   float* __restrict__ nrm, int E) {
    int i = blockIdx.x * 256 + threadIdx.x;
    if (i < E) nrm[i] = dinv[row[i]] * dinv[col[i]];
}

// Tiled fp32 GEMM: H[N x COLS] = X[N x 128] @ W[128 x COLS].
// Block: 256 threads, tile ROWS x COLS, each thread 4 rows x 4 cols.
template <int ROWS, int COLS>
__global__ __launch_bounds__(256) void gemm_kernel(const float* __restrict__ X,
                                                   const float* __restrict__ W,
                                                   float* __restrict__ H, int N) {
    __shared__ float sX[ROWS * 128];
    __shared__ float sW[128 * COLS];
    const int tid = threadIdx.x;
    const long long row0 = (long long)blockIdx.x * ROWS;

    // stage W [128 x COLS] (row-major), coalesced float4
    {
        const float4* W4 = (const float4*)W;
        float4* s4 = (float4*)sW;
        const int n4 = 128 * COLS / 4;
        for (int i = tid; i < n4; i += 256) s4[i] = W4[i];
    }
    // stage X tile [ROWS x 128] (row-major), coalesced float4
    {
        float4* s4 = (float4*)sX;
        const int n4 = ROWS * 32;
        for (int i = tid; i < n4; i += 256) {
            int r = i >> 5, kq = i & 31;
            long long gr = row0 + r;
            float4 v = make_float4(0.f, 0.f, 0.f, 0.f);
            if (gr < N) v = ((const float4*)(X + gr * 128))[kq];
            s4[i] = v;
        }
    }
    __syncthreads();

    constexpr int CG = COLS / 4;
    const int c0 = (tid % CG) * 4;
    const int r0 = (tid / CG) * 4;

    float acc[4][4];
#pragma unroll
    for (int i = 0; i < 4; ++i)
#pragma unroll
        for (int j = 0; j < 4; ++j) acc[i][j] = 0.f;

    for (int kq = 0; kq < 32; ++kq) {
        float4 xv[4], wv[4];
#pragma unroll
        for (int i = 0; i < 4; ++i) xv[i] = *(const float4*)&sX[(r0 + i) * 128 + kq * 4];
#pragma unroll
        for (int j = 0; j < 4; ++j) wv[j] = *(const float4*)&sW[(kq * 4 + j) * COLS + c0];
#pragma unroll
        for (int i = 0; i < 4; ++i) {
            acc[i][0] += xv[i].x * wv[0].x + xv[i].y * wv[1].x + xv[i].z * wv[2].x + xv[i].w * wv[3].x;
            acc[i][1] += xv[i].x * wv[0].y + xv[i].y * wv[1].y + xv[i].z * wv[2].y + xv[i].w * wv[3].y;
            acc[i][2] += xv[i].x * wv[0].z + xv[i].y * wv[1].z + xv[i].z * wv[2].z + xv[i].w * wv[3].z;
            acc[i][3] += xv[i].x * wv[0].w + xv[i].y * wv[1].w + xv[i].z * wv[2].w + xv[i].w * wv[3].w;
        }
    }

#pragma unroll
    for (int i = 0; i < 4; ++i) {
        long long gr = row0 + r0 + i;
        if (gr < N) {
            float4 o = make_float4(acc[i][0], acc[i][1], acc[i][2], acc[i][3]);
            *(float4*)&H[gr * COLS + c0] = o;
        }
    }
}

// Scatter-add: out[col[e]][:] += norm[e] * H[row[e]][:]
template <int C>
__global__ __launch_bounds__(256) void scatter_kernel(const float* __restrict__ H,
                                                      const int* __restrict__ row,
                                                      const int* __restrict__ col,
                                                      const float* __restrict__ nrm,
                                                      float* __restrict__ out, int E) {
    constexpr int LPE = C / 4;        // lanes per edge
    constexpr int EPB = 256 / LPE;    // edges per block
    const int lane = threadIdx.x % LPE;
    const int esub = threadIdx.x / LPE;
    const long long e = (long long)blockIdx.x * EPB + esub;
    if (e >= E) return;
    const int r = row[e];
    const int c = col[e];
    const float w = nrm[e];
    float4 v = ((const float4*)(H + (size_t)r * C))[lane];
    float* o = out + (size_t)c * C + lane * 4;
    atomicAdd(o + 0, v.x * w);
    atomicAdd(o + 1, v.y * w);
    atomicAdd(o + 2, v.z * w);
    atomicAdd(o + 3, v.w * w);
}

// agg[i][c] = (agg[i][c] + H[i][c]*dinv[i]^2 + b[c]), optional ReLU, in place.
template <int C, bool RELU>
__global__ __launch_bounds__(256) void final_kernel(float* __restrict__ agg,
                                                    const float* __restrict__ H,
                                                    const float* __restrict__ dinv,
                                                    const float* __restrict__ b, int N) {
    constexpr int CQ = C / 4;
    int idx = blockIdx.x * 256 + threadIdx.x;   // over N*CQ float4s
    if (idx >= N * CQ) return;
    int i = idx / CQ, cq = idx % CQ;
    float d = dinv[i];
    float d2 = d * d;
    float4 a = ((float4*)agg)[idx];
    float4 h = ((const float4*)H)[idx];
    float4 bb = ((const float4*)b)[cq];
    float4 o;
    o.x = a.x + h.x * d2 + bb.x;
    o.y = a.y + h.y * d2 + bb.y;
    o.z = a.z + h.z * d2 + bb.z;
    o.w = a.w + h.w * d2 + bb.w;
    if (RELU) {
        o.x = fmaxf(o.x, 0.f);
        o.y = fmaxf(o.y, 0.f);
        o.z = fmaxf(o.z, 0.f);
        o.w = fmaxf(o.w, 0.f);
    }
    ((float4*)agg)[idx] = o;
}

static inline int cdiv(long long a, long long b) { return (int)((a + b - 1) / b); }

extern "C" void kernel_launch(void* const* d_in, const int* in_sizes, int n_in,
                              void* d_out, int out_size, void* d_ws, size_t ws_size,
                              hipStream_t stream) {
    const float* x  = (const float*)d_in[0];
    const float* W1 = (const float*)d_in[1];
    const float* b1 = (const float*)d_in[2];
    const float* W2 = (const float*)d_in[3];
    const float* b2 = (const float*)d_in[4];
    const int*   ei = (const int*)d_in[5];

    const int N = in_sizes[0] / 128;   // 100000
    const int E = in_sizes[5] / 2;     // 1600000
    const int* rows = ei;              // edge_index[0] = source
    const int* cols = ei + E;          // edge_index[1] = target

    // workspace layout
    char* ws = (char*)d_ws;
    size_t off = 0;
    auto alloc = [&](size_t bytes) {
        size_t p = off;
        off = (off + bytes + 255) & ~(size_t)255;
        return p;
    };
    float* dinv = (float*)(ws + alloc((size_t)N * 4));            // deg -> dinv in place
    float* nrm  = (float*)(ws + alloc((size_t)E * 4));            // per-edge norm
    float* H    = (float*)(ws + alloc((size_t)N * 128 * 4));      // h1, later h2
    float* AGG  = (float*)(ws + alloc((size_t)N * 128 * 4));      // agg1 -> x2
    (void)ws_size;

    float* OUT = (float*)d_out;

    // 1) degree + dinv + per-edge norm
    hipMemsetAsync(dinv, 0, (size_t)N * 4, stream);
    deg_kernel<<<cdiv(E, 256), 256, 0, stream>>>(cols, dinv, E);
    dinv_kernel<<<cdiv(N, 256), 256, 0, stream>>>(dinv, N);
    norm_kernel<<<cdiv(E, 256), 256, 0, stream>>>(rows, cols, dinv, nrm, E);

    // 2) layer 1: h1 = x@W1 ; agg1 = scatter ; x2 = relu(agg1 + self + b1)
    gemm_kernel<32, 128><<<cdiv(N, 32), 256, 0, stream>>>(x, W1, H, N);
    hipMemsetAsync(AGG, 0, (size_t)N * 128 * 4, stream);
    scatter_kernel<128><<<cdiv(E, 8), 256, 0, stream>>>(H, rows, cols, nrm, AGG, E);
    final_kernel<128, true><<<cdiv((long long)N * 32, 256), 256, 0, stream>>>(AGG, H, dinv, b1, N);

    // 3) layer 2: h2 = x2@W2 ; out = scatter + self + b2
    gemm_kernel<64, 64><<<cdiv(N, 64), 256, 0, stream>>>(AGG, W2, H, N);
    hipMemsetAsync(OUT, 0, (size_t)N * 64 * 4, stream);
    scatter_kernel<64><<<cdiv(E, 16), 256, 0, stream>>>(H, rows, cols, nrm, OUT, E);
    final_kernel<64, false><<<cdiv((long long)N * 16, 256), 256, 0, stream>>>(OUT, H, dinv, b2, N);
}

// Round 2
// 577.137 us; speedup vs baseline: 7.5985x; 7.5985x over previous
//
#include <hip/hip_runtime.h>

// ---------------------------------------------------------------------------
// GCN 2-layer forward, pull-style (no float atomics):
//   cnt[c] = indegree  ->  base = exscan(cnt)  ->  srcSorted (CSR by dest)
//   dinv = rsqrt(cnt+1)
//   h1 = x@W1
//   x2[c] = relu( dinv[c]*( sum_e dinv[src]h1[src] + dinv[c]h1[c] ) + b1 )
//   h2 = x2@W2 ; out analogous (no relu)
// ---------------------------------------------------------------------------

__global__ __launch_bounds__(256) void count_kernel(const int* __restrict__ col,
                                                    int* __restrict__ cnt, int E) {
    int i = blockIdx.x * 256 + threadIdx.x;
    if (i < E) atomicAdd(&cnt[col[i]], 1);
}

__global__ __launch_bounds__(256) void dinv_kernel(const int* __restrict__ cnt,
                                                   float* __restrict__ dinv, int N) {
    int i = blockIdx.x * 256 + threadIdx.x;
    if (i < N) dinv[i] = rsqrtf((float)cnt[i] + 1.0f);   // +1 self-loop
}

// Per-block exclusive scan of cnt -> base, block total -> sums[b]
__global__ __launch_bounds__(256) void scan_block_kernel(const int* __restrict__ cnt,
                                                         int* __restrict__ base,
                                                         int* __restrict__ sums, int N) {
    __shared__ int s[256];
    int tid = threadIdx.x;
    int i = blockIdx.x * 256 + tid;
    int v = (i < N) ? cnt[i] : 0;
    s[tid] = v;
    __syncthreads();
#pragma unroll
    for (int d = 1; d < 256; d <<= 1) {
        int t = (tid >= d) ? s[tid - d] : 0;
        __syncthreads();
        s[tid] += t;
        __syncthreads();
    }
    if (i < N) base[i] = s[tid] - v;          // exclusive within block
    if (tid == 255) sums[blockIdx.x] = s[255];
}

// Single-block exclusive scan of sums[nb] in place (nb <= 512)
__global__ __launch_bounds__(512) void scan_sums_kernel(int* __restrict__ sums, int nb) {
    __shared__ int s[512];
    int tid = threadIdx.x;
    int v = (tid < nb) ? sums[tid] : 0;
    s[tid] = v;
    __syncthreads();
#pragma unroll
    for (int d = 1; d < 512; d <<= 1) {
        int t = (tid >= d) ? s[tid - d] : 0;
        __syncthreads();
        s[tid] += t;
        __syncthreads();
    }
    if (tid < nb) sums[tid] = s[tid] - v;     // exclusive
}

__global__ __launch_bounds__(256) void add_offsets_kernel(int* __restrict__ base,
                                                          const int* __restrict__ sums,
                                                          const int* __restrict__ cnt, int N) {
    int i = blockIdx.x * 256 + threadIdx.x;
    if (i < N) {
        int v = base[i] + sums[i >> 8];
        base[i] = v;
        if (i == N - 1) base[N] = v + cnt[i]; // = E
    }
}

__global__ __launch_bounds__(256) void fill_kernel(const int* __restrict__ row,
                                                   const int* __restrict__ col,
                                                   const int* __restrict__ base,
                                                   int* __restrict__ cursor,
                                                   int* __restrict__ srcSorted, int E) {
    int e = blockIdx.x * 256 + threadIdx.x;
    if (e < E) {
        int c = col[e];
        int idx = base[c] + atomicAdd(&cursor[c], 1);
        srcSorted[idx] = row[e];
    }
}

// Tiled fp32 GEMM: H[N x COLS] = X[N x 128] @ W[128 x COLS].
template <int ROWS, int COLS>
__global__ __launch_bounds__(256) void gemm_kernel(const float* __restrict__ X,
                                                   const float* __restrict__ W,
                                                   float* __restrict__ H, int N) {
    __shared__ float sX[ROWS * 128];
    __shared__ float sW[128 * COLS];
    const int tid = threadIdx.x;
    const long long row0 = (long long)blockIdx.x * ROWS;

    {
        const float4* W4 = (const float4*)W;
        float4* s4 = (float4*)sW;
        const int n4 = 128 * COLS / 4;
        for (int i = tid; i < n4; i += 256) s4[i] = W4[i];
    }
    {
        float4* s4 = (float4*)sX;
        const int n4 = ROWS * 32;
        for (int i = tid; i < n4; i += 256) {
            int r = i >> 5, kq = i & 31;
            long long gr = row0 + r;
            float4 v = make_float4(0.f, 0.f, 0.f, 0.f);
            if (gr < N) v = ((const float4*)(X + gr * 128))[kq];
            s4[i] = v;
        }
    }
    __syncthreads();

    constexpr int CG = COLS / 4;
    const int c0 = (tid % CG) * 4;
    const int r0 = (tid / CG) * 4;

    float acc[4][4];
#pragma unroll
    for (int i = 0; i < 4; ++i)
#pragma unroll
        for (int j = 0; j < 4; ++j) acc[i][j] = 0.f;

    for (int kq = 0; kq < 32; ++kq) {
        float4 xv[4], wv[4];
#pragma unroll
        for (int i = 0; i < 4; ++i) xv[i] = *(const float4*)&sX[(r0 + i) * 128 + kq * 4];
#pragma unroll
        for (int j = 0; j < 4; ++j) wv[j] = *(const float4*)&sW[(kq * 4 + j) * COLS + c0];
#pragma unroll
        for (int i = 0; i < 4; ++i) {
            acc[i][0] += xv[i].x * wv[0].x + xv[i].y * wv[1].x + xv[i].z * wv[2].x + xv[i].w * wv[3].x;
            acc[i][1] += xv[i].x * wv[0].y + xv[i].y * wv[1].y + xv[i].z * wv[2].y + xv[i].w * wv[3].y;
            acc[i][2] += xv[i].x * wv[0].z + xv[i].y * wv[1].z + xv[i].z * wv[2].z + xv[i].w * wv[3].z;
            acc[i][3] += xv[i].x * wv[0].w + xv[i].y * wv[1].w + xv[i].z * wv[2].w + xv[i].w * wv[3].w;
        }
    }

#pragma unroll
    for (int i = 0; i < 4; ++i) {
        long long gr = row0 + r0 + i;
        if (gr < N) {
            float4 o = make_float4(acc[i][0], acc[i][1], acc[i][2], acc[i][3]);
            *(float4*)&H[gr * COLS + c0] = o;
        }
    }
}

// Pull aggregation, C/4 lanes per node, one float4 per lane.
// out[n] = dinv[n]*(sum_e dinv[src]*H[src] + dinv[n]*H[n]) + b  (opt ReLU)
template <int C, bool RELU>
__global__ __launch_bounds__(256) void agg_kernel(const float* __restrict__ H,
                                                  const int* __restrict__ srcSorted,
                                                  const int* __restrict__ base,
                                                  const float* __restrict__ dinv,
                                                  const float* __restrict__ b,
                                                  float* __restrict__ out, int N) {
    constexpr int G = C / 4;          // lanes per node
    constexpr int NPB = 256 / G;      // nodes per block
    const int lane = threadIdx.x % G;
    const int sub = threadIdx.x / G;
    const int n = blockIdx.x * NPB + sub;
    if (n >= N) return;

    const int s = base[n];
    const int e = base[n + 1];
    const float4* H4 = (const float4*)H;

    float4 acc = make_float4(0.f, 0.f, 0.f, 0.f);
    int i = s;
    for (; i + 1 < e; i += 2) {       // unroll x2 for ILP on the gather chain
        int s0 = srcSorted[i], s1 = srcSorted[i + 1];
        float w0 = dinv[s0], w1 = dinv[s1];
        float4 v0 = H4[(size_t)s0 * G + lane];
        float4 v1 = H4[(size_t)s1 * G + lane];
        acc.x += w0 * v0.x + w1 * v1.x;
        acc.y += w0 * v0.y + w1 * v1.y;
        acc.z += w0 * v0.z + w1 * v1.z;
        acc.w += w0 * v0.w + w1 * v1.w;
    }
    if (i < e) {
        int s0 = srcSorted[i];
        float w0 = dinv[s0];
        float4 v0 = H4[(size_t)s0 * G + lane];
        acc.x += w0 * v0.x;
        acc.y += w0 * v0.y;
        acc.z += w0 * v0.z;
        acc.w += w0 * v0.w;
    }

    const float dn = dinv[n];
    float4 hv = H4[(size_t)n * G + lane];
    float4 bb = ((const float4*)b)[lane];
    float4 o;
    o.x = dn * (acc.x + dn * hv.x) + bb.x;
    o.y = dn * (acc.y + dn * hv.y) + bb.y;
    o.z = dn * (acc.z + dn * hv.z) + bb.z;
    o.w = dn * (acc.w + dn * hv.w) + bb.w;
    if (RELU) {
        o.x = fmaxf(o.x, 0.f);
        o.y = fmaxf(o.y, 0.f);
        o.z = fmaxf(o.z, 0.f);
        o.w = fmaxf(o.w, 0.f);
    }
    ((float4*)out)[(size_t)n * G + lane] = o;
}

static inline int cdiv(long long a, long long b) { return (int)((a + b - 1) / b); }

extern "C" void kernel_launch(void* const* d_in, const int* in_sizes, int n_in,
                              void* d_out, int out_size, void* d_ws, size_t ws_size,
                              hipStream_t stream) {
    const float* x  = (const float*)d_in[0];
    const float* W1 = (const float*)d_in[1];
    const float* b1 = (const float*)d_in[2];
    const float* W2 = (const float*)d_in[3];
    const float* b2 = (const float*)d_in[4];
    const int*   ei = (const int*)d_in[5];

    const int N = in_sizes[0] / 128;   // 100000
    const int E = in_sizes[5] / 2;     // 1600000
    const int* rows = ei;              // edge_index[0] = source
    const int* cols = ei + E;          // edge_index[1] = target

    const int nbN = cdiv(N, 256);      // 391 <= 512

    // workspace layout
    char* ws = (char*)d_ws;
    size_t off = 0;
    auto alloc = [&](size_t bytes) {
        size_t p = off;
        off = (off + bytes + 255) & ~(size_t)255;
        return p;
    };
    int*   cnt    = (int*)(ws + alloc((size_t)N * 4));
    int*   cursor = (int*)(ws + alloc((size_t)N * 4));
    int*   base   = (int*)(ws + alloc((size_t)(N + 1) * 4));
    int*   sums   = (int*)(ws + alloc((size_t)512 * 4));
    float* dinv   = (float*)(ws + alloc((size_t)N * 4));
    int*   srcS   = (int*)(ws + alloc((size_t)E * 4));
    float* H      = (float*)(ws + alloc((size_t)N * 128 * 4));  // h1, later h2
    float* X2     = (float*)(ws + alloc((size_t)N * 128 * 4));  // relu'd layer-1 out
    (void)ws_size;

    float* OUT = (float*)d_out;

    // --- CSR by destination + dinv (shared by both layers) ---
    hipMemsetAsync(cnt, 0, (size_t)N * 4, stream);
    hipMemsetAsync(cursor, 0, (size_t)N * 4, stream);
    count_kernel<<<cdiv(E, 256), 256, 0, stream>>>(cols, cnt, E);
    dinv_kernel<<<nbN, 256, 0, stream>>>(cnt, dinv, N);
    scan_block_kernel<<<nbN, 256, 0, stream>>>(cnt, base, sums, N);
    scan_sums_kernel<<<1, 512, 0, stream>>>(sums, nbN);
    add_offsets_kernel<<<nbN, 256, 0, stream>>>(base, sums, cnt, N);
    fill_kernel<<<cdiv(E, 256), 256, 0, stream>>>(rows, cols, base, cursor, srcS, E);

    // --- layer 1 ---
    gemm_kernel<32, 128><<<cdiv(N, 32), 256, 0, stream>>>(x, W1, H, N);
    agg_kernel<128, true><<<cdiv(N, 8), 256, 0, stream>>>(H, srcS, base, dinv, b1, X2, N);

    // --- layer 2 ---
    gemm_kernel<64, 64><<<cdiv(N, 64), 256, 0, stream>>>(X2, W2, H, N);
    agg_kernel<64, false><<<cdiv(N, 16), 256, 0, stream>>>(H, srcS, base, dinv, b2, OUT, N);
}

// Round 3
// 484.969 us; speedup vs baseline: 9.0426x; 1.1900x over previous
//
#include <hip/hip_runtime.h>
#include <hip/hip_fp16.h>

// ---------------------------------------------------------------------------
// GCN 2-layer forward, pull-style, fp16 feature gather:
//   CSR-by-dest build (count/scan/fill)  [reused by both layers]
//   h1 = x@W1 (fp32 compute, fp16 store)
//   x2 = relu( dinv*(sum dinv[s]h1[s] + dinv*h1[n]) + b1 )   [fp32]
//   h2 = x2@W2 (fp16 store) ; out analogous, no relu          [fp32 out]
// ---------------------------------------------------------------------------

__global__ __launch_bounds__(256) void count_kernel(const int* __restrict__ col,
                                                    int* __restrict__ cnt, int E) {
    int i = blockIdx.x * 256 + threadIdx.x;
    if (i < E) atomicAdd(&cnt[col[i]], 1);
}

__global__ __launch_bounds__(256) void dinv_kernel(const int* __restrict__ cnt,
                                                   float* __restrict__ dinv, int N) {
    int i = blockIdx.x * 256 + threadIdx.x;
    if (i < N) dinv[i] = rsqrtf((float)cnt[i] + 1.0f);   // +1 self-loop
}

__global__ __launch_bounds__(256) void scan_block_kernel(const int* __restrict__ cnt,
                                                         int* __restrict__ base,
                                                         int* __restrict__ sums, int N) {
    __shared__ int s[256];
    int tid = threadIdx.x;
    int i = blockIdx.x * 256 + tid;
    int v = (i < N) ? cnt[i] : 0;
    s[tid] = v;
    __syncthreads();
#pragma unroll
    for (int d = 1; d < 256; d <<= 1) {
        int t = (tid >= d) ? s[tid - d] : 0;
        __syncthreads();
        s[tid] += t;
        __syncthreads();
    }
    if (i < N) base[i] = s[tid] - v;
    if (tid == 255) sums[blockIdx.x] = s[255];
}

__global__ __launch_bounds__(512) void scan_sums_kernel(int* __restrict__ sums, int nb) {
    __shared__ int s[512];
    int tid = threadIdx.x;
    int v = (tid < nb) ? sums[tid] : 0;
    s[tid] = v;
    __syncthreads();
#pragma unroll
    for (int d = 1; d < 512; d <<= 1) {
        int t = (tid >= d) ? s[tid - d] : 0;
        __syncthreads();
        s[tid] += t;
        __syncthreads();
    }
    if (tid < nb) sums[tid] = s[tid] - v;
}

__global__ __launch_bounds__(256) void add_offsets_kernel(int* __restrict__ base,
                                                          const int* __restrict__ sums,
                                                          const int* __restrict__ cnt, int N) {
    int i = blockIdx.x * 256 + threadIdx.x;
    if (i < N) {
        int v = base[i] + sums[i >> 8];
        base[i] = v;
        if (i == N - 1) base[N] = v + cnt[i]; // = E
    }
}

// cursor pre-initialized to base via d2d copy
__global__ __launch_bounds__(256) void fill_kernel(const int* __restrict__ row,
                                                   const int* __restrict__ col,
                                                   int* __restrict__ cursor,
                                                   int* __restrict__ srcSorted, int E) {
    int e = blockIdx.x * 256 + threadIdx.x;
    if (e < E) {
        int idx = atomicAdd(&cursor[col[e]], 1);
        srcSorted[idx] = row[e];
    }
}

// Tiled fp32 GEMM: H16[N x COLS] = half(X[N x 128] @ W[128 x COLS]).
template <int ROWS, int COLS>
__global__ __launch_bounds__(256) void gemm_kernel(const float* __restrict__ X,
                                                   const float* __restrict__ W,
                                                   __half* __restrict__ H16, int N) {
    __shared__ float sX[ROWS * 128];
    __shared__ float sW[128 * COLS];
    const int tid = threadIdx.x;
    const long long row0 = (long long)blockIdx.x * ROWS;

    {
        const float4* W4 = (const float4*)W;
        float4* s4 = (float4*)sW;
        const int n4 = 128 * COLS / 4;
        for (int i = tid; i < n4; i += 256) s4[i] = W4[i];
    }
    {
        float4* s4 = (float4*)sX;
        const int n4 = ROWS * 32;
        for (int i = tid; i < n4; i += 256) {
            int r = i >> 5, kq = i & 31;
            long long gr = row0 + r;
            float4 v = make_float4(0.f, 0.f, 0.f, 0.f);
            if (gr < N) v = ((const float4*)(X + gr * 128))[kq];
            s4[i] = v;
        }
    }
    __syncthreads();

    constexpr int CG = COLS / 4;
    const int c0 = (tid % CG) * 4;
    const int r0 = (tid / CG) * 4;

    float acc[4][4];
#pragma unroll
    for (int i = 0; i < 4; ++i)
#pragma unroll
        for (int j = 0; j < 4; ++j) acc[i][j] = 0.f;

    for (int kq = 0; kq < 32; ++kq) {
        float4 xv[4], wv[4];
#pragma unroll
        for (int i = 0; i < 4; ++i) xv[i] = *(const float4*)&sX[(r0 + i) * 128 + kq * 4];
#pragma unroll
        for (int j = 0; j < 4; ++j) wv[j] = *(const float4*)&sW[(kq * 4 + j) * COLS + c0];
#pragma unroll
        for (int i = 0; i < 4; ++i) {
            acc[i][0] += xv[i].x * wv[0].x + xv[i].y * wv[1].x + xv[i].z * wv[2].x + xv[i].w * wv[3].x;
            acc[i][1] += xv[i].x * wv[0].y + xv[i].y * wv[1].y + xv[i].z * wv[2].y + xv[i].w * wv[3].y;
            acc[i][2] += xv[i].x * wv[0].z + xv[i].y * wv[1].z + xv[i].z * wv[2].z + xv[i].w * wv[3].z;
            acc[i][3] += xv[i].x * wv[0].w + xv[i].y * wv[1].w + xv[i].z * wv[2].w + xv[i].w * wv[3].w;
        }
    }

#pragma unroll
    for (int i = 0; i < 4; ++i) {
        long long gr = row0 + r0 + i;
        if (gr < N) {
            union { __half2 h[2]; uint2 u; } pk;
            pk.h[0] = __half2(__float2half_rn(acc[i][0]), __float2half_rn(acc[i][1]));
            pk.h[1] = __half2(__float2half_rn(acc[i][2]), __float2half_rn(acc[i][3]));
            *(uint2*)&H16[gr * COLS + c0] = pk.u;
        }
    }
}

__device__ inline void fma8(float (&a)[8], uint4 v, float w) {
    union { uint4 u; __half2 h[4]; } cv;
    cv.u = v;
#pragma unroll
    for (int q = 0; q < 4; ++q) {
        a[2 * q]     = fmaf(w, __low2float(cv.h[q]),  a[2 * q]);
        a[2 * q + 1] = fmaf(w, __high2float(cv.h[q]), a[2 * q + 1]);
    }
}

// Pull aggregation: G = C/8 lanes per node, 8 channels (one uint4 of halves) per lane.
// out[n] = dinv[n]*(sum_e dinv[s]*H[s] + dinv[n]*H[n]) + b   (opt ReLU), fp32 out.
template <int C, bool RELU>
__global__ __launch_bounds__(256) void agg_kernel(const __half* __restrict__ H16,
                                                  const int* __restrict__ srcSorted,
                                                  const int* __restrict__ base,
                                                  const float* __restrict__ dinv,
                                                  const float* __restrict__ b,
                                                  float* __restrict__ out, int N) {
    constexpr int G = C / 8;          // lanes per node
    constexpr int NPB = 256 / G;      // nodes per block
    const int lane = threadIdx.x % G;
    const int sub = threadIdx.x / G;
    const int n = blockIdx.x * NPB + sub;
    if (n >= N) return;

    const uint4* H4 = (const uint4*)H16;   // one uint4 = 8 halves
    const int s = base[n];
    const int e = base[n + 1];

    float acc[8];
#pragma unroll
    for (int q = 0; q < 8; ++q) acc[q] = 0.f;

    int i = s;
    for (; i + 3 < e; i += 4) {       // 4 independent gather chains in flight
        int s0 = srcSorted[i], s1 = srcSorted[i + 1];
        int s2 = srcSorted[i + 2], s3 = srcSorted[i + 3];
        float w0 = dinv[s0], w1 = dinv[s1], w2 = dinv[s2], w3 = dinv[s3];
        uint4 v0 = H4[(size_t)s0 * G + lane];
        uint4 v1 = H4[(size_t)s1 * G + lane];
        uint4 v2 = H4[(size_t)s2 * G + lane];
        uint4 v3 = H4[(size_t)s3 * G + lane];
        fma8(acc, v0, w0);
        fma8(acc, v1, w1);
        fma8(acc, v2, w2);
        fma8(acc, v3, w3);
    }
    for (; i < e; ++i) {
        int s0 = srcSorted[i];
        float w0 = dinv[s0];
        uint4 v0 = H4[(size_t)s0 * G + lane];
        fma8(acc, v0, w0);
    }

    const float dn = dinv[n];
    uint4 hv = H4[(size_t)n * G + lane];
    union { uint4 u; __half2 h[4]; } cv;
    cv.u = hv;
    float hf[8];
#pragma unroll
    for (int q = 0; q < 4; ++q) {
        hf[2 * q] = __low2float(cv.h[q]);
        hf[2 * q + 1] = __high2float(cv.h[q]);
    }
    const float4 bb0 = ((const float4*)b)[lane * 2];
    const float4 bb1 = ((const float4*)b)[lane * 2 + 1];
    const float* bbp = (const float*)&bb0;   // bb0/bb1 contiguous on stack? avoid UB: handle explicitly
    (void)bbp;

    float o[8];
#pragma unroll
    for (int q = 0; q < 8; ++q) o[q] = dn * (acc[q] + dn * hf[q]);
    o[0] += bb0.x; o[1] += bb0.y; o[2] += bb0.z; o[3] += bb0.w;
    o[4] += bb1.x; o[5] += bb1.y; o[6] += bb1.z; o[7] += bb1.w;
    if (RELU) {
#pragma unroll
        for (int q = 0; q < 8; ++q) o[q] = fmaxf(o[q], 0.f);
    }
    float4 st0 = make_float4(o[0], o[1], o[2], o[3]);
    float4 st1 = make_float4(o[4], o[5], o[6], o[7]);
    float4* op = (float4*)(out + (size_t)n * C + lane * 8);
    op[0] = st0;
    op[1] = st1;
}

static inline int cdiv(long long a, long long b) { return (int)((a + b - 1) / b); }

extern "C" void kernel_launch(void* const* d_in, const int* in_sizes, int n_in,
                              void* d_out, int out_size, void* d_ws, size_t ws_size,
                              hipStream_t stream) {
    const float* x  = (const float*)d_in[0];
    const float* W1 = (const float*)d_in[1];
    const float* b1 = (const float*)d_in[2];
    const float* W2 = (const float*)d_in[3];
    const float* b2 = (const float*)d_in[4];
    const int*   ei = (const int*)d_in[5];

    const int N = in_sizes[0] / 128;   // 100000
    const int E = in_sizes[5] / 2;     // 1600000
    const int* rows = ei;              // edge_index[0] = source
    const int* cols = ei + E;          // edge_index[1] = target

    const int nbN = cdiv(N, 256);      // 391 <= 512

    // workspace layout
    char* ws = (char*)d_ws;
    size_t off = 0;
    auto alloc = [&](size_t bytes) {
        size_t p = off;
        off = (off + bytes + 255) & ~(size_t)255;
        return p;
    };
    int*    cnt    = (int*)(ws + alloc((size_t)N * 4));
    int*    cursor = (int*)(ws + alloc((size_t)(N + 1) * 4));
    int*    base   = (int*)(ws + alloc((size_t)(N + 1) * 4));
    int*    sums   = (int*)(ws + alloc((size_t)512 * 4));
    float*  dinv   = (float*)(ws + alloc((size_t)N * 4));
    int*    srcS   = (int*)(ws + alloc((size_t)E * 4));
    __half* H16    = (__half*)(ws + alloc((size_t)N * 128 * 2));  // h1, later h2
    float*  X2     = (float*)(ws + alloc((size_t)N * 128 * 4));   // relu'd layer-1 out
    (void)ws_size;

    float* OUT = (float*)d_out;

    // --- CSR by destination + dinv (shared by both layers) ---
    hipMemsetAsync(cnt, 0, (size_t)N * 4, stream);
    count_kernel<<<cdiv(E, 256), 256, 0, stream>>>(cols, cnt, E);
    dinv_kernel<<<nbN, 256, 0, stream>>>(cnt, dinv, N);
    scan_block_kernel<<<nbN, 256, 0, stream>>>(cnt, base, sums, N);
    scan_sums_kernel<<<1, 512, 0, stream>>>(sums, nbN);
    add_offsets_kernel<<<nbN, 256, 0, stream>>>(base, sums, cnt, N);
    hipMemcpyAsync(cursor, base, (size_t)N * 4, hipMemcpyDeviceToDevice, stream);
    fill_kernel<<<cdiv(E, 256), 256, 0, stream>>>(rows, cols, cursor, srcS, E);

    // --- layer 1 ---
    gemm_kernel<32, 128><<<cdiv(N, 32), 256, 0, stream>>>(x, W1, H16, N);
    agg_kernel<128, true><<<cdiv(N, 16), 256, 0, stream>>>(H16, srcS, base, dinv, b1, X2, N);

    // --- layer 2 ---
    gemm_kernel<64, 64><<<cdiv(N, 64), 256, 0, stream>>>(X2, W2, H16, N);
    agg_kernel<64, false><<<cdiv(N, 32), 256, 0, stream>>>(H16, srcS, base, dinv, b2, OUT, N);
}

// Round 4
// 371.502 us; speedup vs baseline: 11.8045x; 1.3054x over previous
//
#include <hip/hip_runtime.h>
#include <hip/hip_fp16.h>

typedef _Float16 half8 __attribute__((ext_vector_type(8)));
typedef float floatx4 __attribute__((ext_vector_type(4)));

// ---------------------------------------------------------------------------
// GCN 2-layer, pull-style, fp16 gather + fp16 MFMA GEMMs + XCD-ranged CSR fill
// ---------------------------------------------------------------------------

// ---- CSR build, destination-range partitioned so each XCD (blockIdx&7) owns
// ---- a contiguous node range: writes stay in that XCD's L2, no ping-pong.
__global__ __launch_bounds__(256) void count2_kernel(const int* __restrict__ col,
                                                     int* __restrict__ cnt,
                                                     int E, int N, int NS, int CHUNKS) {
    const int xcd = blockIdx.x & 7;
    const int lo = xcd * NS;
    const int hi = min(lo + NS, N);
    const int stride = CHUNKS * 256;
    for (int e = (blockIdx.x >> 3) * 256 + threadIdx.x; e < E; e += stride) {
        int c = col[e];
        if (c >= lo && c < hi) atomicAdd(&cnt[c], 1);
    }
}

__global__ __launch_bounds__(256) void fill2_kernel(const int* __restrict__ row,
                                                    const int* __restrict__ col,
                                                    int* __restrict__ cursor,
                                                    int* __restrict__ srcSorted,
                                                    int E, int N, int NS, int CHUNKS) {
    const int xcd = blockIdx.x & 7;
    const int lo = xcd * NS;
    const int hi = min(lo + NS, N);
    const int stride = CHUNKS * 256;
    for (int e = (blockIdx.x >> 3) * 256 + threadIdx.x; e < E; e += stride) {
        int c = col[e];
        if (c >= lo && c < hi) {
            int idx = atomicAdd(&cursor[c], 1);
            srcSorted[idx] = row[e];
        }
    }
}

__global__ __launch_bounds__(256) void dinv_kernel(const int* __restrict__ cnt,
                                                   float* __restrict__ dinv, int N) {
    int i = blockIdx.x * 256 + threadIdx.x;
    if (i < N) dinv[i] = rsqrtf((float)cnt[i] + 1.0f);   // +1 self-loop
}

__global__ __launch_bounds__(256) void scan_block_kernel(const int* __restrict__ cnt,
                                                         int* __restrict__ base,
                                                         int* __restrict__ sums, int N) {
    __shared__ int s[256];
    int tid = threadIdx.x;
    int i = blockIdx.x * 256 + tid;
    int v = (i < N) ? cnt[i] : 0;
    s[tid] = v;
    __syncthreads();
#pragma unroll
    for (int d = 1; d < 256; d <<= 1) {
        int t = (tid >= d) ? s[tid - d] : 0;
        __syncthreads();
        s[tid] += t;
        __syncthreads();
    }
    if (i < N) base[i] = s[tid] - v;
    if (tid == 255) sums[blockIdx.x] = s[255];
}

__global__ __launch_bounds__(512) void scan_sums_kernel(int* __restrict__ sums, int nb) {
    __shared__ int s[512];
    int tid = threadIdx.x;
    int v = (tid < nb) ? sums[tid] : 0;
    s[tid] = v;
    __syncthreads();
#pragma unroll
    for (int d = 1; d < 512; d <<= 1) {
        int t = (tid >= d) ? s[tid - d] : 0;
        __syncthreads();
        s[tid] += t;
        __syncthreads();
    }
    if (tid < nb) sums[tid] = s[tid] - v;
}

__global__ __launch_bounds__(256) void add_offsets_kernel(int* __restrict__ base,
                                                          const int* __restrict__ sums,
                                                          const int* __restrict__ cnt, int N) {
    int i = blockIdx.x * 256 + threadIdx.x;
    if (i < N) {
        int v = base[i] + sums[i >> 8];
        base[i] = v;
        if (i == N - 1) base[N] = v + cnt[i]; // = E
    }
}

// ---- W [128 x C] fp32 row-major  ->  WT [C x 128] fp16, k-index XOR-swizzled
// ---- (swizzle: k' = k ^ ((c&7)<<3), i.e. 16B blocks permuted within the row)
__global__ __launch_bounds__(256) void wtrans_kernel(const float* __restrict__ W,
                                                     __half* __restrict__ WT, int C) {
    int idx = blockIdx.x * 256 + threadIdx.x;
    if (idx >= 128 * C) return;
    int k = idx / C, c = idx % C;        // consecutive tid -> consecutive c (coalesced read)
    float v = W[idx];
    WT[c * 128 + (k ^ ((c & 7) << 3))] = __float2half_rn(v);
}

// ---- fp16 MFMA GEMM: H[N x COLS] = X[N x 128] @ W[128 x COLS], fp32 accum.
// A frag: lane l elem j = A[l&15][(l>>4)*8+j]; B frag: B[(l>>4)*8+j][l&15];
// D: reg r -> row (l>>4)*4+r, col l&15.   Block: 64 rows, 4 waves (2M x 2N).
template <int COLS, typename XT>
__global__ __launch_bounds__(256) void mfma_gemm(const XT* __restrict__ X,
                                                 const __half* __restrict__ WT,
                                                 __half* __restrict__ H, int N) {
    __shared__ _Float16 sX[64 * 128];
    __shared__ _Float16 sW[COLS * 128];
    const int tid = threadIdx.x;
    const int row0 = blockIdx.x * 64;

    // stage pre-swizzled WT (linear copy)
    {
        const uint4* src = (const uint4*)WT;
        uint4* dst = (uint4*)sW;
        for (int i = tid; i < COLS * 16; i += 256) dst[i] = src[i];
    }
    // stage X tile 64x128 -> fp16, swizzled
    for (int cidx = tid; cidx < 1024; cidx += 256) {
        int r = cidx >> 4, k8 = cidx & 15;
        int gr = row0 + r;
        half8 h;
#pragma unroll
        for (int q = 0; q < 8; ++q) h[q] = (_Float16)0.f;
        if (gr < N) {
            if constexpr (sizeof(XT) == 4) {
                const float4* p = (const float4*)((const float*)X + (size_t)gr * 128 + k8 * 8);
                float4 f0 = p[0], f1 = p[1];
                h[0] = (_Float16)f0.x; h[1] = (_Float16)f0.y;
                h[2] = (_Float16)f0.z; h[3] = (_Float16)f0.w;
                h[4] = (_Float16)f1.x; h[5] = (_Float16)f1.y;
                h[6] = (_Float16)f1.z; h[7] = (_Float16)f1.w;
            } else {
                h = *(const half8*)((const _Float16*)X + (size_t)gr * 128 + k8 * 8);
            }
        }
        *(half8*)(sX + r * 128 + ((k8 * 8) ^ ((r & 7) << 3))) = h;
    }
    __syncthreads();

    const int w = tid >> 6;
    const int lane = tid & 63;
    const int l15 = lane & 15, l4 = lane >> 4;
    constexpr int WCOLS = COLS / 2;
    constexpr int NCB = WCOLS / 16;          // 4 (C=128) or 2 (C=64)
    const int wr = (w >> 1) * 32;
    const int wc = (w & 1) * WCOLS;

    half8 a[2][4];
#pragma unroll
    for (int rb = 0; rb < 2; ++rb) {
        int r = wr + rb * 16 + l15;
#pragma unroll
        for (int kb = 0; kb < 4; ++kb)
            a[rb][kb] = *(const half8*)(sX + r * 128 + ((kb * 32 + l4 * 8) ^ ((r & 7) << 3)));
    }

    floatx4 acc[2][NCB];
#pragma unroll
    for (int rb = 0; rb < 2; ++rb)
#pragma unroll
        for (int cb = 0; cb < NCB; ++cb) acc[rb][cb] = (floatx4)(0.f);

#pragma unroll
    for (int cb = 0; cb < NCB; ++cb) {
        int c = wc + cb * 16 + l15;
#pragma unroll
        for (int kb = 0; kb < 4; ++kb) {
            half8 b = *(const half8*)(sW + c * 128 + ((kb * 32 + l4 * 8) ^ ((c & 7) << 3)));
#pragma unroll
            for (int rb = 0; rb < 2; ++rb)
                acc[rb][cb] = __builtin_amdgcn_mfma_f32_16x16x32_f16(a[rb][kb], b, acc[rb][cb], 0, 0, 0);
        }
    }

#pragma unroll
    for (int rb = 0; rb < 2; ++rb)
#pragma unroll
        for (int cb = 0; cb < NCB; ++cb)
#pragma unroll
            for (int r = 0; r < 4; ++r) {
                int gr = row0 + wr + rb * 16 + l4 * 4 + r;
                if (gr < N) {
                    int gc = wc + cb * 16 + l15;
                    H[(size_t)gr * COLS + gc] = __float2half_rn(acc[rb][cb][r]);
                }
            }
}

__device__ inline void fma8(float (&a)[8], uint4 v, float w) {
    union { uint4 u; __half2 h[4]; } cv;
    cv.u = v;
#pragma unroll
    for (int q = 0; q < 4; ++q) {
        a[2 * q]     = fmaf(w, __low2float(cv.h[q]),  a[2 * q]);
        a[2 * q + 1] = fmaf(w, __high2float(cv.h[q]), a[2 * q + 1]);
    }
}

// ---- Pull aggregation: G = C/8 lanes/node, 8 channels (uint4 of halves) each.
// out[n] = dinv[n]*(sum dinv[s]H[s] + dinv[n]H[n]) + b   (opt ReLU); OT out.
template <int C, bool RELU, typename OT>
__global__ __launch_bounds__(256) void agg_kernel(const __half* __restrict__ H16,
                                                  const int* __restrict__ srcSorted,
                                                  const int* __restrict__ base,
                                                  const float* __restrict__ dinv,
                                                  const float* __restrict__ b,
                                                  OT* __restrict__ out, int N) {
    constexpr int G = C / 8;
    constexpr int NPB = 256 / G;
    const int lane = threadIdx.x % G;
    const int sub = threadIdx.x / G;
    const int n = blockIdx.x * NPB + sub;
    if (n >= N) return;

    const uint4* H4 = (const uint4*)H16;
    const int s = base[n];
    const int e = base[n + 1];

    float acc[8];
#pragma unroll
    for (int q = 0; q < 8; ++q) acc[q] = 0.f;

    int i = s;
    for (; i + 3 < e; i += 4) {
        int s0 = srcSorted[i], s1 = srcSorted[i + 1];
        int s2 = srcSorted[i + 2], s3 = srcSorted[i + 3];
        float w0 = dinv[s0], w1 = dinv[s1], w2 = dinv[s2], w3 = dinv[s3];
        uint4 v0 = H4[(size_t)s0 * G + lane];
        uint4 v1 = H4[(size_t)s1 * G + lane];
        uint4 v2 = H4[(size_t)s2 * G + lane];
        uint4 v3 = H4[(size_t)s3 * G + lane];
        fma8(acc, v0, w0);
        fma8(acc, v1, w1);
        fma8(acc, v2, w2);
        fma8(acc, v3, w3);
    }
    for (; i < e; ++i) {
        int s0 = srcSorted[i];
        float w0 = dinv[s0];
        fma8(acc, H4[(size_t)s0 * G + lane], w0);
    }

    const float dn = dinv[n];
    uint4 hv = H4[(size_t)n * G + lane];
    union { uint4 u; __half2 h[4]; } cv;
    cv.u = hv;
    float o[8];
#pragma unroll
    for (int q = 0; q < 4; ++q) {
        o[2 * q]     = dn * (acc[2 * q]     + dn * __low2float(cv.h[q]));
        o[2 * q + 1] = dn * (acc[2 * q + 1] + dn * __high2float(cv.h[q]));
    }
    const float4 bb0 = ((const float4*)b)[lane * 2];
    const float4 bb1 = ((const float4*)b)[lane * 2 + 1];
    o[0] += bb0.x; o[1] += bb0.y; o[2] += bb0.z; o[3] += bb0.w;
    o[4] += bb1.x; o[5] += bb1.y; o[6] += bb1.z; o[7] += bb1.w;
    if (RELU) {
#pragma unroll
        for (int q = 0; q < 8; ++q) o[q] = fmaxf(o[q], 0.f);
    }
    if constexpr (sizeof(OT) == 2) {
        half8 st;
#pragma unroll
        for (int q = 0; q < 8; ++q) st[q] = (_Float16)o[q];
        *(half8*)((_Float16*)out + (size_t)n * C + lane * 8) = st;
    } else {
        float4* op = (float4*)((float*)out + (size_t)n * C + lane * 8);
        op[0] = make_float4(o[0], o[1], o[2], o[3]);
        op[1] = make_float4(o[4], o[5], o[6], o[7]);
    }
}

static inline int cdiv(long long a, long long b) { return (int)((a + b - 1) / b); }

extern "C" void kernel_launch(void* const* d_in, const int* in_sizes, int n_in,
                              void* d_out, int out_size, void* d_ws, size_t ws_size,
                              hipStream_t stream) {
    const float* x  = (const float*)d_in[0];
    const float* W1 = (const float*)d_in[1];
    const float* b1 = (const float*)d_in[2];
    const float* W2 = (const float*)d_in[3];
    const float* b2 = (const float*)d_in[4];
    const int*   ei = (const int*)d_in[5];

    const int N = in_sizes[0] / 128;   // 100000
    const int E = in_sizes[5] / 2;     // 1600000
    const int* rows = ei;              // edge_index[0] = source
    const int* cols = ei + E;          // edge_index[1] = target

    const int nbN = cdiv(N, 256);      // 391
    const int NS = cdiv(N, 8);         // 12500 nodes per XCD range
    const int CHUNKS = 128;            // blocks per range-pass

    char* ws = (char*)d_ws;
    size_t off = 0;
    auto alloc = [&](size_t bytes) {
        size_t p = off;
        off = (off + bytes + 255) & ~(size_t)255;
        return p;
    };
    int*      cnt    = (int*)(ws + alloc((size_t)N * 4));
    int*      cursor = (int*)(ws + alloc((size_t)(N + 1) * 4));
    int*      base   = (int*)(ws + alloc((size_t)(N + 1) * 4));
    int*      sums   = (int*)(ws + alloc((size_t)512 * 4));
    float*    dinv   = (float*)(ws + alloc((size_t)N * 4));
    int*      srcS   = (int*)(ws + alloc((size_t)E * 4));
    __half*   WT1    = (__half*)(ws + alloc((size_t)128 * 128 * 2));
    __half*   WT2    = (__half*)(ws + alloc((size_t)128 * 64 * 2));
    __half*   H16    = (__half*)(ws + alloc((size_t)N * 128 * 2));  // h1, then h2
    __half*   X2h    = (__half*)(ws + alloc((size_t)N * 128 * 2));  // relu'd layer-1
    (void)ws_size;

    float* OUT = (float*)d_out;

    // --- CSR by destination + dinv (shared by both layers) ---
    hipMemsetAsync(cnt, 0, (size_t)N * 4, stream);
    count2_kernel<<<8 * CHUNKS, 256, 0, stream>>>(cols, cnt, E, N, NS, CHUNKS);
    dinv_kernel<<<nbN, 256, 0, stream>>>(cnt, dinv, N);
    scan_block_kernel<<<nbN, 256, 0, stream>>>(cnt, base, sums, N);
    scan_sums_kernel<<<1, 512, 0, stream>>>(sums, nbN);
    add_offsets_kernel<<<nbN, 256, 0, stream>>>(base, sums, cnt, N);
    hipMemcpyAsync(cursor, base, (size_t)N * 4, hipMemcpyDeviceToDevice, stream);
    fill2_kernel<<<8 * CHUNKS, 256, 0, stream>>>(rows, cols, cursor, srcS, E, N, NS, CHUNKS);

    // --- weight prep (fp16, transposed, swizzled) ---
    wtrans_kernel<<<cdiv(128 * 128, 256), 256, 0, stream>>>(W1, WT1, 128);
    wtrans_kernel<<<cdiv(128 * 64, 256), 256, 0, stream>>>(W2, WT2, 64);

    // --- layer 1 ---
    mfma_gemm<128, float><<<cdiv(N, 64), 256, 0, stream>>>(x, WT1, H16, N);
    agg_kernel<128, true, __half><<<cdiv(N, 16), 256, 0, stream>>>(H16, srcS, base, dinv, b1, X2h, N);

    // --- layer 2 ---
    mfma_gemm<64, _Float16><<<cdiv(N, 64), 256, 0, stream>>>((const _Float16*)X2h, WT2, H16, N);
    agg_kernel<64, false, float><<<cdiv(N, 32), 256, 0, stream>>>(H16, srcS, base, dinv, b2, OUT, N);
}